// Round 2
// baseline (7905.104 us; speedup 1.0000x reference)
//
#include <hip/hip_runtime.h>
#include <cstdint>
#include <cstddef>

#define HD 128
#define EMBD 96
#define SELD 32
#define PD 64
#define NPOS 513
#define GITERS 6

__device__ __forceinline__ float sigm(float x) { return 1.0f / (1.0f + __expf(-x)); }

// ---------------- setup kernels ----------------

__global__ void k_deg(const int* __restrict__ ei, int* __restrict__ deg, int E) {
    int e = blockIdx.x * 256 + threadIdx.x;
    if (e < E) atomicAdd(&deg[ei[E + e]], 1);
}

// single-block exclusive scan over deg[0..N) -> rp[0..N]
__launch_bounds__(1024)
__global__ void k_scan(const int* __restrict__ deg, int* __restrict__ rp, int N, int E) {
    __shared__ int sc[1024];
    int t = threadIdx.x;
    int chunk = (N + 1023) / 1024;
    int lo = t * chunk, hi = min(N, lo + chunk);
    int sum = 0;
    for (int i = lo; i < hi; ++i) sum += deg[i];
    sc[t] = sum;
    __syncthreads();
    for (int off = 1; off < 1024; off <<= 1) {
        int v = (t >= off) ? sc[t - off] : 0;
        __syncthreads();
        sc[t] += v;
        __syncthreads();
    }
    int base = sc[t] - sum; // exclusive
    int run = base;
    for (int i = lo; i < hi; ++i) { rp[i] = run; run += deg[i]; }
    if (t == 1023) rp[N] = base + sum; // == E
}

__global__ void k_fill(const int* __restrict__ ei, const int* __restrict__ et,
                       const int* __restrict__ ep, const int* __restrict__ rp,
                       int* __restrict__ cursor, int* __restrict__ esrc,
                       int* __restrict__ epack, int E) {
    int e = blockIdx.x * 256 + threadIdx.x;
    if (e < E) {
        int d = ei[E + e];
        int pos = atomicAdd(&cursor[d], 1);
        int idx = rp[d] + pos;
        esrc[idx] = ei[e];
        epack[idx] = (et[e] << 10) | ep[e];
    }
}

// gate_table[p][j] = 2*sigmoid(pos_enc[p] @ Wg + bg)[j]
__global__ void k_gate(const float* __restrict__ pe, const float* __restrict__ Wg,
                       const float* __restrict__ bg, float* __restrict__ gateT) {
    int p = blockIdx.x;
    int j = threadIdx.x;
    float acc = bg[j];
    #pragma unroll 8
    for (int k = 0; k < PD; ++k) acc += pe[p * PD + k] * Wg[k * HD + j];
    gateT[p * HD + j] = 2.0f * sigm(acc);
}

// transpose [384,128] -> [128,384] for both GRU weight matrices
__global__ void k_transpose(const float* __restrict__ Wih, const float* __restrict__ Whh,
                            float* __restrict__ WihT, float* __restrict__ WhhT) {
    int id = blockIdx.x * 256 + threadIdx.x;
    const int SZ = 3 * HD * HD;
    if (id < SZ) {
        int j = id / HD, k = id % HD;
        WihT[k * (3 * HD) + j] = Wih[id];
    } else if (id < 2 * SZ) {
        int i2 = id - SZ;
        int j = i2 / HD, k = i2 % HD;
        WhhT[k * (3 * HD) + j] = Whh[i2];
    }
}

// h = [emb[x] | selectors]
__global__ void k_init(const int* __restrict__ xidx, const float* __restrict__ sel,
                       const float* __restrict__ emb, float* __restrict__ h, int N) {
    int id = blockIdx.x * 256 + threadIdx.x;
    if (id < N * HD) {
        int n = id >> 7, j = id & 127;
        h[id] = (j < EMBD) ? emb[(size_t)xidx[n] * EMBD + j]
                           : sel[(size_t)n * SELD + (j - EMBD)];
    }
}

// ---------------- per-iteration kernels ----------------

// CSR gather + per-type LDS accumulate + Wt matvec + bias + mean-denominator.
// One block = 16 dst nodes, 4 waves; wave w owns nodes dn ≡ w (mod 4).
__launch_bounds__(256, 2)
__global__ void k_agg(const int* __restrict__ rp, const int* __restrict__ esrc,
                      const int* __restrict__ epack, const float* __restrict__ h,
                      const float* __restrict__ gateT, const float* __restrict__ Wt,
                      const float* __restrict__ bt, float* __restrict__ agg, int N) {
    __shared__ float S[3][16][129];
    __shared__ int cnt[16][3];
    int tid = threadIdx.x;
    int wave = tid >> 6, lane = tid & 63;
    int d0 = blockIdx.x * 16;

    for (int dn = wave; dn < 16; dn += 4) {
        int d = d0 + dn;
        if (d >= N) continue;
        int start = rp[d], end = rp[d + 1];
        int c = lane * 2;
        float a0x = 0.f, a0y = 0.f, a1x = 0.f, a1y = 0.f, a2x = 0.f, a2y = 0.f;
        int c0i = 0, c1i = 0, c2i = 0;
        for (int e = start; e < end; ++e) {
            int s = esrc[e];
            int pk = epack[e];
            int t = pk >> 10;
            int p = pk & 1023;
            float2 hv = *(const float2*)(h + (size_t)s * HD + c);
            float2 gv = *(const float2*)(gateT + (size_t)p * HD + c);
            float mx = hv.x * gv.x, my = hv.y * gv.y;
            if (t == 0)      { a0x += mx; a0y += my; c0i++; }
            else if (t == 1) { a1x += mx; a1y += my; c1i++; }
            else             { a2x += mx; a2y += my; c2i++; }
        }
        S[0][dn][c] = a0x; S[0][dn][c + 1] = a0y;
        S[1][dn][c] = a1x; S[1][dn][c + 1] = a1y;
        S[2][dn][c] = a2x; S[2][dn][c + 1] = a2y;
        if (lane == 0) { cnt[dn][0] = c0i; cnt[dn][1] = c1i; cnt[dn][2] = c2i; }
    }
    __syncthreads();

    // matvec: tx -> 8 cols, ty -> node
    int tx = tid & 15, ty = tid >> 4;
    int c0 = tx * 8;
    float acc[8];
    #pragma unroll
    for (int j = 0; j < 8; ++j) acc[j] = 0.0f;
    #pragma unroll
    for (int t = 0; t < 3; ++t) {
        const float* Wp = Wt + (size_t)t * HD * HD;
        for (int k = 0; k < HD; ++k) {
            float sv = S[t][ty][k];
            float4 b0 = *(const float4*)(Wp + (size_t)k * HD + c0);
            float4 b1 = *(const float4*)(Wp + (size_t)k * HD + c0 + 4);
            acc[0] += sv * b0.x; acc[1] += sv * b0.y;
            acc[2] += sv * b0.z; acc[3] += sv * b0.w;
            acc[4] += sv * b1.x; acc[5] += sv * b1.y;
            acc[6] += sv * b1.z; acc[7] += sv * b1.w;
        }
    }
    int d = d0 + ty;
    if (d < N) {
        float n0 = (float)cnt[ty][0], n1 = (float)cnt[ty][1], n2 = (float)cnt[ty][2];
        float inv = 1.0f / fmaxf(n0 + n1 + n2, 1.0f);
        #pragma unroll
        for (int j = 0; j < 8; ++j) {
            int col = c0 + j;
            float v = acc[j] + n0 * bt[col] + n1 * bt[HD + col] + n2 * bt[2 * HD + col];
            agg[(size_t)d * HD + col] = v * inv;
        }
    }
}

__device__ __forceinline__ void gate_gemm(const float As[32][132], const float Hs[32][132],
                                          const float* __restrict__ Bi, const float* __restrict__ Bh,
                                          int r0, int c0, float ai[2][8], float ah[2][8]) {
    #pragma unroll
    for (int i = 0; i < 2; ++i)
        #pragma unroll
        for (int j = 0; j < 8; ++j) { ai[i][j] = 0.0f; ah[i][j] = 0.0f; }
    #pragma unroll 4
    for (int k = 0; k < HD; ++k) {
        float a0 = As[r0][k], a1 = As[r0 + 1][k];
        float h0 = Hs[r0][k], h1 = Hs[r0 + 1][k];
        float4 biA = *(const float4*)(Bi + (size_t)k * 384 + c0);
        float4 biB = *(const float4*)(Bi + (size_t)k * 384 + c0 + 4);
        float4 bhA = *(const float4*)(Bh + (size_t)k * 384 + c0);
        float4 bhB = *(const float4*)(Bh + (size_t)k * 384 + c0 + 4);
        float bi[8] = {biA.x, biA.y, biA.z, biA.w, biB.x, biB.y, biB.z, biB.w};
        float bh[8] = {bhA.x, bhA.y, bhA.z, bhA.w, bhB.x, bhB.y, bhB.z, bhB.w};
        #pragma unroll
        for (int j = 0; j < 8; ++j) {
            ai[0][j] += a0 * bi[j];
            ai[1][j] += a1 * bi[j];
            ah[0][j] += h0 * bh[j];
            ah[1][j] += h1 * bh[j];
        }
    }
}

// fully fused GRU cell; updates h in place (tile staged in LDS first)
__launch_bounds__(256, 2)
__global__ void k_gru(const float* __restrict__ agg, const float* __restrict__ WihT,
                      const float* __restrict__ WhhT, const float* __restrict__ bih,
                      const float* __restrict__ bhh, float* __restrict__ h, int N) {
    __shared__ float As[32][132];
    __shared__ float Hs[32][132];
    int tid = threadIdx.x;
    int tx = tid & 15, ty = tid >> 4;
    int row0 = blockIdx.x * 32;
    int c0 = tx * 8;
    int r0 = ty * 2;

    for (int i = tid; i < 32 * 32; i += 256) {
        int r = i >> 5;
        int cc = (i & 31) * 4;
        int gr = row0 + r;
        float4 va = make_float4(0.f, 0.f, 0.f, 0.f);
        float4 vh = make_float4(0.f, 0.f, 0.f, 0.f);
        if (gr < N) {
            va = *(const float4*)(agg + (size_t)gr * HD + cc);
            vh = *(const float4*)(h + (size_t)gr * HD + cc);
        }
        *(float4*)(&As[r][cc]) = va;
        *(float4*)(&Hs[r][cc]) = vh;
    }
    __syncthreads();

    float ai[2][8], ah[2][8], rr[2][8], zz[2][8];

    // r gate
    gate_gemm(As, Hs, WihT, WhhT, r0, c0, ai, ah);
    #pragma unroll
    for (int i = 0; i < 2; ++i)
        #pragma unroll
        for (int j = 0; j < 8; ++j)
            rr[i][j] = sigm(ai[i][j] + ah[i][j] + bih[c0 + j] + bhh[c0 + j]);

    // z gate
    gate_gemm(As, Hs, WihT + HD, WhhT + HD, r0, c0, ai, ah);
    #pragma unroll
    for (int i = 0; i < 2; ++i)
        #pragma unroll
        for (int j = 0; j < 8; ++j)
            zz[i][j] = sigm(ai[i][j] + ah[i][j] + bih[HD + c0 + j] + bhh[HD + c0 + j]);

    // n gate + update
    gate_gemm(As, Hs, WihT + 2 * HD, WhhT + 2 * HD, r0, c0, ai, ah);
    #pragma unroll
    for (int i = 0; i < 2; ++i) {
        int row = row0 + r0 + i;
        if (row >= N) continue;
        #pragma unroll
        for (int j = 0; j < 8; ++j) {
            int col = c0 + j;
            float i_n = ai[i][j] + bih[2 * HD + col];
            float h_n = ah[i][j] + bhh[2 * HD + col];
            float nn = tanhf(i_n + rr[i][j] * h_n);
            float hv = Hs[r0 + i][col];
            h[(size_t)row * HD + col] = (1.0f - zz[i][j]) * nn + zz[i][j] * hv;
        }
    }
}

// feats = [h | emb[x] | sel]; logits = relu(feats@W1+b1)@W2 + b2
__launch_bounds__(256, 2)
__global__ void k_final(const float* __restrict__ h, const int* __restrict__ xidx,
                        const float* __restrict__ sel, const float* __restrict__ emb,
                        const float* __restrict__ W1, const float* __restrict__ b1,
                        const float* __restrict__ W2, const float* __restrict__ b2,
                        float* __restrict__ out, int N) {
    __shared__ float Fs[32][260];
    int tid = threadIdx.x;
    int tx = tid & 15, ty = tid >> 4;
    int row0 = blockIdx.x * 32;
    int c0 = tx * 8;
    int r0 = ty * 2;

    for (int i = tid; i < 32 * 256; i += 256) {
        int r = i >> 8, c = i & 255;
        int n = row0 + r;
        float v = 0.0f;
        if (n < N) {
            if (c < HD) v = h[(size_t)n * HD + c];
            else if (c < HD + EMBD) v = emb[(size_t)xidx[n] * EMBD + (c - HD)];
            else v = sel[(size_t)n * SELD + (c - HD - EMBD)];
        }
        Fs[r][c] = v;
    }
    __syncthreads();

    float acc[2][8];
    #pragma unroll
    for (int i = 0; i < 2; ++i)
        #pragma unroll
        for (int j = 0; j < 8; ++j) acc[i][j] = 0.0f;
    #pragma unroll 4
    for (int k = 0; k < 2 * HD; ++k) {
        float a0 = Fs[r0][k], a1 = Fs[r0 + 1][k];
        float4 bA = *(const float4*)(W1 + (size_t)k * HD + c0);
        float4 bB = *(const float4*)(W1 + (size_t)k * HD + c0 + 4);
        float bv[8] = {bA.x, bA.y, bA.z, bA.w, bB.x, bB.y, bB.z, bB.w};
        #pragma unroll
        for (int j = 0; j < 8; ++j) {
            acc[0][j] += a0 * bv[j];
            acc[1][j] += a1 * bv[j];
        }
    }
    #pragma unroll
    for (int i = 0; i < 2; ++i) {
        float p = 0.0f;
        #pragma unroll
        for (int j = 0; j < 8; ++j) {
            int col = c0 + j;
            float hv = fmaxf(acc[i][j] + b1[col], 0.0f);
            p += hv * W2[col];
        }
        // reduce across the 16 tx lanes (tx = low 4 bits of lane id)
        #pragma unroll
        for (int off = 8; off > 0; off >>= 1) p += __shfl_down(p, off);
        int row = row0 + r0 + i;
        if (tx == 0 && row < N) out[row] = p + b2[0];
    }
}

// ---------------- launcher ----------------

extern "C" void kernel_launch(void* const* d_in, const int* in_sizes, int n_in,
                              void* d_out, int out_size, void* d_ws, size_t ws_size,
                              hipStream_t stream) {
    const int*   xidx = (const int*)d_in[0];
    const float* sel  = (const float*)d_in[1];
    const int*   ei   = (const int*)d_in[2];
    const int*   et   = (const int*)d_in[3];
    const int*   ep   = (const int*)d_in[4];
    const float* emb  = (const float*)d_in[5];
    const float* pe   = (const float*)d_in[6];
    const float* Wg   = (const float*)d_in[7];
    const float* bg   = (const float*)d_in[8];
    const float* Wt   = (const float*)d_in[9];
    const float* bt   = (const float*)d_in[10];
    const float* Wih  = (const float*)d_in[11];
    const float* Whh  = (const float*)d_in[12];
    const float* bih  = (const float*)d_in[13];
    const float* bhh  = (const float*)d_in[14];
    const float* W1   = (const float*)d_in[15];
    const float* b1   = (const float*)d_in[16];
    const float* W2   = (const float*)d_in[17];
    const float* b2   = (const float*)d_in[18];

    const int N = in_sizes[0];
    const int E = in_sizes[3];
    const size_t NH = (size_t)N * HD;

    float* ws    = (float*)d_ws;
    float* h     = ws;                     // NH
    float* agg   = h + NH;                 // NH
    float* gateT = agg + NH;               // NPOS*HD
    float* WihT  = gateT + (size_t)NPOS * HD;
    float* WhhT  = WihT + 3 * HD * HD;
    int*   deg    = (int*)(WhhT + 3 * HD * HD); // N
    int*   rp     = deg + N;               // N+1
    int*   cursor = rp + N + 1;            // N
    int*   esrc   = cursor + N;            // E
    int*   epack  = esrc + E;              // E

    // ---- setup: CSR build + tables + h init ----
    hipMemsetAsync(deg, 0, (size_t)N * sizeof(int), stream);
    hipMemsetAsync(cursor, 0, (size_t)N * sizeof(int), stream);
    k_deg<<<(E + 255) / 256, 256, 0, stream>>>(ei, deg, E);
    k_scan<<<1, 1024, 0, stream>>>(deg, rp, N, E);
    k_fill<<<(E + 255) / 256, 256, 0, stream>>>(ei, et, ep, rp, cursor, esrc, epack, E);
    k_gate<<<NPOS, HD, 0, stream>>>(pe, Wg, bg, gateT);
    k_transpose<<<(2 * 3 * HD * HD + 255) / 256, 256, 0, stream>>>(Wih, Whh, WihT, WhhT);
    k_init<<<(N * HD + 255) / 256, 256, 0, stream>>>(xidx, sel, emb, h, N);

    for (int it = 0; it < GITERS; ++it) {
        k_agg<<<(N + 15) / 16, 256, 0, stream>>>(rp, esrc, epack, h, gateT, Wt, bt, agg, N);
        k_gru<<<(N + 31) / 32, 256, 0, stream>>>(agg, WihT, WhhT, bih, bhh, h, N);
    }

    k_final<<<(N + 31) / 32, 256, 0, stream>>>(h, xidx, sel, emb, W1, b1, W2, b2,
                                               (float*)d_out, N);
}

// Round 3
// 2789.406 us; speedup vs baseline: 2.8340x; 2.8340x over previous
//
#include <hip/hip_runtime.h>
#include <cstdint>
#include <cstddef>

#define HD 128
#define EMBD 96
#define SELD 32
#define PD 64
#define NPOS 513
#define GITERS 6

typedef __attribute__((ext_vector_type(8))) short bf16x8;
typedef __attribute__((ext_vector_type(4))) float f32x4;

__device__ __forceinline__ float sigm(float x) { return 1.0f / (1.0f + __expf(-x)); }

// fp32 -> bf16 (round-to-nearest-even), bit pattern in a short
__device__ __forceinline__ short f2bf(float x) {
    uint32_t u = __float_as_uint(x);
    uint32_t r = (u + 0x7fffu + ((u >> 16) & 1u)) >> 16;
    return (short)r;
}
__device__ __forceinline__ float bf2f(uint16_t s) {
    return __uint_as_float(((uint32_t)s) << 16);
}

// ---------------- setup kernels ----------------

__global__ void k_deg(const int* __restrict__ ei, int* __restrict__ deg, int E) {
    int e = blockIdx.x * 256 + threadIdx.x;
    if (e < E) atomicAdd(&deg[ei[E + e]], 1);
}

__launch_bounds__(1024)
__global__ void k_scan(const int* __restrict__ deg, int* __restrict__ rp, int N, int E) {
    __shared__ int sc[1024];
    int t = threadIdx.x;
    int chunk = (N + 1023) / 1024;
    int lo = t * chunk, hi = min(N, lo + chunk);
    int sum = 0;
    for (int i = lo; i < hi; ++i) sum += deg[i];
    sc[t] = sum;
    __syncthreads();
    for (int off = 1; off < 1024; off <<= 1) {
        int v = (t >= off) ? sc[t - off] : 0;
        __syncthreads();
        sc[t] += v;
        __syncthreads();
    }
    int base = sc[t] - sum;
    int run = base;
    for (int i = lo; i < hi; ++i) { rp[i] = run; run += deg[i]; }
    if (t == 1023) rp[N] = base + sum;
}

__global__ void k_fill(const int* __restrict__ ei, const int* __restrict__ et,
                       const int* __restrict__ ep, const int* __restrict__ rp,
                       int* __restrict__ cursor, int* __restrict__ esrc,
                       int* __restrict__ epack, int E) {
    int e = blockIdx.x * 256 + threadIdx.x;
    if (e < E) {
        int d = ei[E + e];
        int pos = atomicAdd(&cursor[d], 1);
        int idx = rp[d] + pos;
        esrc[idx] = ei[e];
        epack[idx] = (et[e] << 10) | ep[e];
    }
}

// gate_table[p][j] = 2*sigmoid(pos_enc[p] @ Wg + bg)[j]  (fp32)
__global__ void k_gate(const float* __restrict__ pe, const float* __restrict__ Wg,
                       const float* __restrict__ bg, float* __restrict__ gateT) {
    int p = blockIdx.x;
    int j = threadIdx.x;
    float acc = bg[j];
    #pragma unroll 8
    for (int k = 0; k < PD; ++k) acc += pe[p * PD + k] * Wg[k * HD + j];
    gateT[p * HD + j] = 2.0f * sigm(acc);
}

// bf16 weight prep:
//  WtT [t][n][k] = Wt[t][k][n]          (3*128*128)
//  Wihb = Wih (row-major [384][128], already B^T layout)
//  Whhb = Whh
//  W1T [n][k] = W1[k][n]                (128 x 256)
__global__ void k_prep(const float* __restrict__ Wt, const float* __restrict__ Wih,
                       const float* __restrict__ Whh, const float* __restrict__ W1,
                       short* __restrict__ WtT, short* __restrict__ Wihb,
                       short* __restrict__ Whhb, short* __restrict__ W1T) {
    const int SZ = 3 * HD * HD; // 49152
    int id = blockIdx.x * 256 + threadIdx.x;
    if (id < SZ) {
        int t = id / (HD * HD), rem = id % (HD * HD);
        int n = rem / HD, k = rem % HD;
        WtT[id] = f2bf(Wt[t * HD * HD + k * HD + n]);
    } else if (id < 2 * SZ) {
        int i2 = id - SZ;
        Wihb[i2] = f2bf(Wih[i2]);
    } else if (id < 3 * SZ) {
        int i2 = id - 2 * SZ;
        Whhb[i2] = f2bf(Whh[i2]);
    } else if (id < 3 * SZ + 2 * HD * HD) {
        int rem = id - 3 * SZ;
        int n = rem / (2 * HD), k = rem % (2 * HD);
        W1T[rem] = f2bf(W1[k * HD + n]);
    }
}

// h = [emb[x] | selectors] (fp32 master + bf16 copy)
__global__ void k_init(const int* __restrict__ xidx, const float* __restrict__ sel,
                       const float* __restrict__ emb, float* __restrict__ h,
                       short* __restrict__ h_bf, int N) {
    int id = blockIdx.x * 256 + threadIdx.x;
    if (id < N * HD) {
        int n = id >> 7, j = id & 127;
        float v = (j < EMBD) ? emb[(size_t)xidx[n] * EMBD + j]
                             : sel[(size_t)n * SELD + (j - EMBD)];
        h[id] = v;
        h_bf[id] = f2bf(v);
    }
}

// ---------------- per-iteration kernels ----------------

// CSR gather (bf16 h) -> per-type fp32 sums in LDS -> MFMA @ WtT -> bias/mean -> agg_bf
__launch_bounds__(256)
__global__ void k_agg(const int* __restrict__ rp, const int* __restrict__ esrc,
                      const int* __restrict__ epack, const short* __restrict__ h_bf,
                      const float* __restrict__ gateT, const short* __restrict__ WtT,
                      const float* __restrict__ bt, short* __restrict__ agg_bf, int N) {
    __shared__ float S[3][16][132];
    __shared__ int cnt[16][4];
    int tid = threadIdx.x;
    int wave = tid >> 6, lane = tid & 63;
    int d0 = blockIdx.x * 16;

    for (int dn = wave; dn < 16; dn += 4) {
        int d = d0 + dn;
        float a0x = 0.f, a0y = 0.f, a1x = 0.f, a1y = 0.f, a2x = 0.f, a2y = 0.f;
        int c0i = 0, c1i = 0, c2i = 0;
        if (d < N) {
            int start = rp[d], end = rp[d + 1];
            for (int e = start; e < end; ++e) {
                int s = esrc[e];
                int pk = epack[e];
                int t = pk >> 10, p = pk & 1023;
                uint32_t hv = *(const uint32_t*)(h_bf + (size_t)s * HD + 2 * lane);
                float2 gv = *(const float2*)(gateT + (size_t)p * HD + 2 * lane);
                float mx = bf2f((uint16_t)(hv & 0xffffu)) * gv.x;
                float my = bf2f((uint16_t)(hv >> 16)) * gv.y;
                if (t == 0)      { a0x += mx; a0y += my; c0i++; }
                else if (t == 1) { a1x += mx; a1y += my; c1i++; }
                else             { a2x += mx; a2y += my; c2i++; }
            }
        }
        S[0][dn][2 * lane] = a0x; S[0][dn][2 * lane + 1] = a0y;
        S[1][dn][2 * lane] = a1x; S[1][dn][2 * lane + 1] = a1y;
        S[2][dn][2 * lane] = a2x; S[2][dn][2 * lane + 1] = a2y;
        if (lane == 0) { cnt[dn][0] = c0i; cnt[dn][1] = c1i; cnt[dn][2] = c2i; }
    }
    __syncthreads();

    int quad = lane >> 4, m = lane & 15;

    // 12 A-frags from LDS (fp32 -> bf16)
    bf16x8 af[3][4];
    #pragma unroll
    for (int t = 0; t < 3; ++t)
        #pragma unroll
        for (int c = 0; c < 4; ++c) {
            const float* sp = &S[t][m][c * 32 + quad * 8];
            #pragma unroll
            for (int j = 0; j < 8; ++j) af[t][c][j] = f2bf(sp[j]);
        }

    f32x4 acc[2];
    const f32x4 z4 = {0.f, 0.f, 0.f, 0.f};
    acc[0] = z4; acc[1] = z4;
    #pragma unroll
    for (int s = 0; s < 2; ++s) {
        int c0 = (wave * 2 + s) * 16;
        #pragma unroll
        for (int t = 0; t < 3; ++t)
            #pragma unroll
            for (int c = 0; c < 4; ++c) {
                bf16x8 b = *(const bf16x8*)(WtT + ((size_t)t * HD + c0 + m) * HD + c * 32 + quad * 8);
                acc[s] = __builtin_amdgcn_mfma_f32_16x16x32_bf16(af[t][c], b, acc[s], 0, 0, 0);
            }
    }

    #pragma unroll
    for (int s = 0; s < 2; ++s) {
        int col = (wave * 2 + s) * 16 + m;
        float bt0 = bt[col], bt1 = bt[HD + col], bt2 = bt[2 * HD + col];
        #pragma unroll
        for (int r = 0; r < 4; ++r) {
            int mm = quad * 4 + r;
            int d = d0 + mm;
            if (d < N) {
                float n0 = (float)cnt[mm][0], n1 = (float)cnt[mm][1], n2 = (float)cnt[mm][2];
                float inv = 1.0f / fmaxf(n0 + n1 + n2, 1.0f);
                float v = (acc[s][r] + n0 * bt0 + n1 * bt1 + n2 * bt2) * inv;
                agg_bf[(size_t)d * HD + col] = f2bf(v);
            }
        }
    }
}

// fully fused GRU via MFMA; in-place update of h (fp32) and h_bf (bf16)
__launch_bounds__(256)
__global__ void k_gru(const short* __restrict__ agg_bf, short* __restrict__ h_bf,
                      const short* __restrict__ Wihb, const short* __restrict__ Whhb,
                      const float* __restrict__ bih, const float* __restrict__ bhh,
                      float* __restrict__ h, int N) {
    int tid = threadIdx.x;
    int wave = tid >> 6, lane = tid & 63;
    int quad = lane >> 4, m = lane & 15;
    int row0 = blockIdx.x * 16;
    int arow = min(row0 + m, N - 1);

    bf16x8 fa[4], fh[4];
    #pragma unroll
    for (int c = 0; c < 4; ++c) {
        fa[c] = *(const bf16x8*)(agg_bf + (size_t)arow * HD + c * 32 + quad * 8);
        fh[c] = *(const bf16x8*)(h_bf + (size_t)arow * HD + c * 32 + quad * 8);
    }

    f32x4 acc[2][6];
    const f32x4 z4 = {0.f, 0.f, 0.f, 0.f};
    #pragma unroll
    for (int s = 0; s < 2; ++s)
        #pragma unroll
        for (int g = 0; g < 6; ++g) acc[s][g] = z4;

    #pragma unroll
    for (int s = 0; s < 2; ++s) {
        int c0 = (wave * 2 + s) * 16;
        #pragma unroll
        for (int g = 0; g < 3; ++g)
            #pragma unroll
            for (int c = 0; c < 4; ++c) {
                bf16x8 bi = *(const bf16x8*)(Wihb + ((size_t)g * HD + c0 + m) * HD + c * 32 + quad * 8);
                acc[s][g] = __builtin_amdgcn_mfma_f32_16x16x32_bf16(fa[c], bi, acc[s][g], 0, 0, 0);
                bf16x8 bh = *(const bf16x8*)(Whhb + ((size_t)g * HD + c0 + m) * HD + c * 32 + quad * 8);
                acc[s][3 + g] = __builtin_amdgcn_mfma_f32_16x16x32_bf16(fh[c], bh, acc[s][3 + g], 0, 0, 0);
            }
    }

    // all h_bf reads (A-frags) complete in every wave before any store
    __syncthreads();

    #pragma unroll
    for (int s = 0; s < 2; ++s) {
        int col = (wave * 2 + s) * 16 + m;
        float bir = bih[col],          bhr = bhh[col];
        float biz = bih[HD + col],     bhz = bhh[HD + col];
        float bin = bih[2 * HD + col], bhn = bhh[2 * HD + col];
        #pragma unroll
        for (int r = 0; r < 4; ++r) {
            int row = row0 + quad * 4 + r;
            if (row < N) {
                float rr = sigm(acc[s][0][r] + bir + acc[s][3][r] + bhr);
                float zz = sigm(acc[s][1][r] + biz + acc[s][4][r] + bhz);
                float nn = tanhf(acc[s][2][r] + bin + rr * (acc[s][5][r] + bhn));
                size_t idx = (size_t)row * HD + col;
                float hv = h[idx];
                float hp = (1.0f - zz) * nn + zz * hv;
                h[idx] = hp;
                h_bf[idx] = f2bf(hp);
            }
        }
    }
}

// feats=[h|emb[x]|sel] (bf16 frags) @ W1T (MFMA) -> relu -> @W2 + b2
__launch_bounds__(256)
__global__ void k_final(const short* __restrict__ h_bf, const int* __restrict__ xidx,
                        const float* __restrict__ sel, const float* __restrict__ emb,
                        const short* __restrict__ W1T, const float* __restrict__ b1,
                        const float* __restrict__ W2, const float* __restrict__ b2,
                        float* __restrict__ out, int N) {
    __shared__ float red[4][16];
    int tid = threadIdx.x;
    int wave = tid >> 6, lane = tid & 63;
    int quad = lane >> 4, m = lane & 15;
    int row0 = blockIdx.x * 16;
    int arow = min(row0 + m, N - 1);
    int xi = xidx[arow];

    bf16x8 fa[8];
    #pragma unroll
    for (int c = 0; c < 4; ++c)
        fa[c] = *(const bf16x8*)(h_bf + (size_t)arow * HD + c * 32 + quad * 8);
    #pragma unroll
    for (int c = 4; c < 7; ++c) {
        const float* ep = emb + (size_t)xi * EMBD + (c - 4) * 32 + quad * 8;
        #pragma unroll
        for (int j = 0; j < 8; ++j) fa[c][j] = f2bf(ep[j]);
    }
    {
        const float* sp = sel + (size_t)arow * SELD + quad * 8;
        #pragma unroll
        for (int j = 0; j < 8; ++j) fa[7][j] = f2bf(sp[j]);
    }

    f32x4 acc[2];
    const f32x4 z4 = {0.f, 0.f, 0.f, 0.f};
    acc[0] = z4; acc[1] = z4;
    #pragma unroll
    for (int s = 0; s < 2; ++s) {
        int c0 = (wave * 2 + s) * 16;
        #pragma unroll
        for (int c = 0; c < 8; ++c) {
            bf16x8 b = *(const bf16x8*)(W1T + (size_t)(c0 + m) * (2 * HD) + c * 32 + quad * 8);
            acc[s] = __builtin_amdgcn_mfma_f32_16x16x32_bf16(fa[c], b, acc[s], 0, 0, 0);
        }
    }

    float psum[4] = {0.f, 0.f, 0.f, 0.f};
    #pragma unroll
    for (int s = 0; s < 2; ++s) {
        int col = (wave * 2 + s) * 16 + m;
        float b1v = b1[col], w2v = W2[col];
        #pragma unroll
        for (int r = 0; r < 4; ++r)
            psum[r] += fmaxf(acc[s][r] + b1v, 0.0f) * w2v;
    }
    #pragma unroll
    for (int off = 1; off < 16; off <<= 1)
        #pragma unroll
        for (int r = 0; r < 4; ++r) psum[r] += __shfl_xor(psum[r], off);

    if (m == 0) {
        #pragma unroll
        for (int r = 0; r < 4; ++r) red[wave][quad * 4 + r] = psum[r];
    }
    __syncthreads();
    if (tid < 16) {
        int row = row0 + tid;
        if (row < N) out[row] = red[0][tid] + red[1][tid] + red[2][tid] + red[3][tid] + b2[0];
    }
}

// ---------------- launcher ----------------

extern "C" void kernel_launch(void* const* d_in, const int* in_sizes, int n_in,
                              void* d_out, int out_size, void* d_ws, size_t ws_size,
                              hipStream_t stream) {
    const int*   xidx = (const int*)d_in[0];
    const float* sel  = (const float*)d_in[1];
    const int*   ei   = (const int*)d_in[2];
    const int*   et   = (const int*)d_in[3];
    const int*   ep   = (const int*)d_in[4];
    const float* emb  = (const float*)d_in[5];
    const float* pe   = (const float*)d_in[6];
    const float* Wg   = (const float*)d_in[7];
    const float* bg   = (const float*)d_in[8];
    const float* Wt   = (const float*)d_in[9];
    const float* bt   = (const float*)d_in[10];
    const float* Wih  = (const float*)d_in[11];
    const float* Whh  = (const float*)d_in[12];
    const float* bih  = (const float*)d_in[13];
    const float* bhh  = (const float*)d_in[14];
    const float* W1   = (const float*)d_in[15];
    const float* b1   = (const float*)d_in[16];
    const float* W2   = (const float*)d_in[17];
    const float* b2   = (const float*)d_in[18];

    const int N = in_sizes[0];
    const int E = in_sizes[3];
    const size_t NH = (size_t)N * HD;

    char* p = (char*)d_ws;
    float* h      = (float*)p; p += NH * 4;
    short* agg_bf = (short*)p; p += NH * 2;
    short* h_bf   = (short*)p; p += NH * 2;
    float* gateT  = (float*)p; p += (size_t)NPOS * HD * 4;
    short* WtT    = (short*)p; p += 3 * HD * HD * 2;
    short* Wihb   = (short*)p; p += 3 * HD * HD * 2;
    short* Whhb   = (short*)p; p += 3 * HD * HD * 2;
    short* W1T    = (short*)p; p += 2 * HD * HD * 2;
    int* deg      = (int*)p;   p += (size_t)N * 4;
    int* rp       = (int*)p;   p += (size_t)(N + 1) * 4;
    int* cursor   = (int*)p;   p += (size_t)N * 4;
    int* esrc     = (int*)p;   p += (size_t)E * 4;
    int* epack    = (int*)p;

    // ---- setup ----
    hipMemsetAsync(deg, 0, (size_t)N * sizeof(int), stream);
    hipMemsetAsync(cursor, 0, (size_t)N * sizeof(int), stream);
    k_deg<<<(E + 255) / 256, 256, 0, stream>>>(ei, deg, E);
    k_scan<<<1, 1024, 0, stream>>>(deg, rp, N, E);
    k_fill<<<(E + 255) / 256, 256, 0, stream>>>(ei, et, ep, rp, cursor, esrc, epack, E);
    k_gate<<<NPOS, HD, 0, stream>>>(pe, Wg, bg, gateT);
    k_prep<<<(3 * 3 * HD * HD + 2 * HD * HD + 255) / 256, 256, 0, stream>>>(
        Wt, Wih, Whh, W1, WtT, Wihb, Whhb, W1T);
    k_init<<<(N * HD + 255) / 256, 256, 0, stream>>>(xidx, sel, emb, h, h_bf, N);

    const int gB = (N + 15) / 16;
    for (int it = 0; it < GITERS; ++it) {
        k_agg<<<gB, 256, 0, stream>>>(rp, esrc, epack, h_bf, gateT, WtT, bt, agg_bf, N);
        k_gru<<<gB, 256, 0, stream>>>(agg_bf, h_bf, Wihb, Whhb, bih, bhh, h, N);
    }

    k_final<<<gB, 256, 0, stream>>>(h_bf, xidx, sel, emb, W1T, b1, W2, b2, (float*)d_out, N);
}

// Round 4
// 2306.769 us; speedup vs baseline: 3.4269x; 1.2092x over previous
//
#include <hip/hip_runtime.h>
#include <cstdint>
#include <cstddef>

#define HD 128
#define EMBD 96
#define SELD 32
#define PD 64
#define NPOS 513
#define GITERS 6

typedef __attribute__((ext_vector_type(8))) short bf16x8;
typedef __attribute__((ext_vector_type(4))) float f32x4;

__device__ __forceinline__ float sigm(float x) { return 1.0f / (1.0f + __expf(-x)); }

__device__ __forceinline__ short f2bf(float x) {
    uint32_t u = __float_as_uint(x);
    uint32_t r = (u + 0x7fffu + ((u >> 16) & 1u)) >> 16;
    return (short)r;
}
__device__ __forceinline__ float bf2f(uint32_t s) {
    return __uint_as_float(s << 16);
}

// ---------------- setup kernels ----------------

// per-dst total degree + per-type counts
__global__ void k_deg(const int* __restrict__ ei, const int* __restrict__ et,
                      int* __restrict__ deg, int* __restrict__ cnt_t, int E, int N) {
    int e = blockIdx.x * 256 + threadIdx.x;
    if (e < E) {
        int d = ei[E + e];
        atomicAdd(&deg[d], 1);
        atomicAdd(&cnt_t[(size_t)et[e] * N + d], 1);
    }
}

// cntp[n] = (n0, n1, n2, 1/max(deg,1))
__global__ void k_cntp(const int* __restrict__ deg, const int* __restrict__ cnt_t,
                       float4* __restrict__ cntp, int N) {
    int n = blockIdx.x * 256 + threadIdx.x;
    if (n < N) {
        float4 v;
        v.x = (float)cnt_t[n];
        v.y = (float)cnt_t[(size_t)N + n];
        v.z = (float)cnt_t[2 * (size_t)N + n];
        v.w = 1.0f / fmaxf((float)deg[n], 1.0f);
        cntp[n] = v;
    }
}

__launch_bounds__(1024)
__global__ void k_scan(const int* __restrict__ deg, int* __restrict__ rp, int N, int E) {
    __shared__ int sc[1024];
    int t = threadIdx.x;
    int chunk = (N + 1023) / 1024;
    int lo = t * chunk, hi = min(N, lo + chunk);
    int sum = 0;
    for (int i = lo; i < hi; ++i) sum += deg[i];
    sc[t] = sum;
    __syncthreads();
    for (int off = 1; off < 1024; off <<= 1) {
        int v = (t >= off) ? sc[t - off] : 0;
        __syncthreads();
        sc[t] += v;
        __syncthreads();
    }
    int base = sc[t] - sum;
    int run = base;
    for (int i = lo; i < hi; ++i) { rp[i] = run; run += deg[i]; }
    if (t == 1023) rp[N] = base + sum;
}

__global__ void k_fill(const int* __restrict__ ei, const int* __restrict__ et,
                       const int* __restrict__ ep, const int* __restrict__ rp,
                       int* __restrict__ cursor, int* __restrict__ esrc,
                       int* __restrict__ epack, int E) {
    int e = blockIdx.x * 256 + threadIdx.x;
    if (e < E) {
        int d = ei[E + e];
        int pos = atomicAdd(&cursor[d], 1);
        int idx = rp[d] + pos;
        esrc[idx] = ei[e];
        epack[idx] = (et[e] << 10) | ep[e];
    }
}

// gate table in bf16: gb[p][j] = bf16(2*sigmoid(pos_enc[p] @ Wg + bg)[j])
__global__ void k_gate(const float* __restrict__ pe, const float* __restrict__ Wg,
                       const float* __restrict__ bg, short* __restrict__ gb) {
    int p = blockIdx.x;
    int j = threadIdx.x;
    float acc = bg[j];
    #pragma unroll 8
    for (int k = 0; k < PD; ++k) acc += pe[p * PD + k] * Wg[k * HD + j];
    gb[p * HD + j] = f2bf(2.0f * sigm(acc));
}

// bf16 weight prep (WtT transposed to [t][n][k]; Wih/Whh already B^T; W1T transposed)
__global__ void k_prep(const float* __restrict__ Wt, const float* __restrict__ Wih,
                       const float* __restrict__ Whh, const float* __restrict__ W1,
                       short* __restrict__ WtT, short* __restrict__ Wihb,
                       short* __restrict__ Whhb, short* __restrict__ W1T) {
    const int SZ = 3 * HD * HD;
    int id = blockIdx.x * 256 + threadIdx.x;
    if (id < SZ) {
        int t = id / (HD * HD), rem = id % (HD * HD);
        int n = rem / HD, k = rem % HD;
        WtT[id] = f2bf(Wt[t * HD * HD + k * HD + n]);
    } else if (id < 2 * SZ) {
        int i2 = id - SZ;
        Wihb[i2] = f2bf(Wih[i2]);
    } else if (id < 3 * SZ) {
        int i2 = id - 2 * SZ;
        Whhb[i2] = f2bf(Whh[i2]);
    } else if (id < 3 * SZ + 2 * HD * HD) {
        int rem = id - 3 * SZ;
        int n = rem / (2 * HD), k = rem % (2 * HD);
        W1T[rem] = f2bf(W1[k * HD + n]);
    }
}

__global__ void k_init(const int* __restrict__ xidx, const float* __restrict__ sel,
                       const float* __restrict__ emb, float* __restrict__ h,
                       short* __restrict__ h_bf, int N) {
    int id = blockIdx.x * 256 + threadIdx.x;
    if (id < N * HD) {
        int n = id >> 7, j = id & 127;
        float v = (j < EMBD) ? emb[(size_t)xidx[n] * EMBD + j]
                             : sel[(size_t)n * SELD + (j - EMBD)];
        h[id] = v;
        h_bf[id] = f2bf(v);
    }
}

// ---------------- per-iteration kernels ----------------

// 1024 threads = 16 waves; wave w gathers dst node d0+w (unroll-4 edge loop),
// writes bf16 per-type sums to LDS; waves 0-7 run the 3-type MFMA + epilogue.
__launch_bounds__(1024)
__global__ void k_agg(const int* __restrict__ rp, const int* __restrict__ esrc,
                      const int* __restrict__ epack, const short* __restrict__ h_bf,
                      const short* __restrict__ gb, const short* __restrict__ WtT,
                      const float* __restrict__ bt, const float4* __restrict__ cntp,
                      short* __restrict__ agg_bf, int N) {
    __shared__ short S[3 * 16 * 136];
    int tid = threadIdx.x;
    int wave = tid >> 6, lane = tid & 63;
    int d0 = blockIdx.x * 16;

    // ---- gather phase: one dst per wave ----
    int d = __builtin_amdgcn_readfirstlane(min(d0 + wave, N - 1));
    bool valid = (d0 + wave) < N;
    float a0x = 0.f, a0y = 0.f, a1x = 0.f, a1y = 0.f, a2x = 0.f, a2y = 0.f;
    int cl = 2 * lane;

    if (valid) {
        int e = rp[d], e1 = rp[d + 1];
        #define ACC1(hv, gv, t)                                              \
            {                                                                \
                float mx = bf2f((hv) & 0xffffu) * bf2f((gv) & 0xffffu);      \
                float my = bf2f((hv) >> 16) * bf2f((gv) >> 16);              \
                if ((t) == 0)      { a0x += mx; a0y += my; }                 \
                else if ((t) == 1) { a1x += mx; a1y += my; }                 \
                else               { a2x += mx; a2y += my; }                 \
            }
        for (; e + 4 <= e1; e += 4) {
            int s0 = esrc[e],     s1 = esrc[e + 1], s2 = esrc[e + 2], s3 = esrc[e + 3];
            int p0 = epack[e],    p1 = epack[e + 1], p2 = epack[e + 2], p3 = epack[e + 3];
            uint32_t h0 = *(const uint32_t*)(h_bf + (size_t)s0 * HD + cl);
            uint32_t h1 = *(const uint32_t*)(h_bf + (size_t)s1 * HD + cl);
            uint32_t h2 = *(const uint32_t*)(h_bf + (size_t)s2 * HD + cl);
            uint32_t h3 = *(const uint32_t*)(h_bf + (size_t)s3 * HD + cl);
            uint32_t g0 = *(const uint32_t*)(gb + (size_t)(p0 & 1023) * HD + cl);
            uint32_t g1 = *(const uint32_t*)(gb + (size_t)(p1 & 1023) * HD + cl);
            uint32_t g2 = *(const uint32_t*)(gb + (size_t)(p2 & 1023) * HD + cl);
            uint32_t g3 = *(const uint32_t*)(gb + (size_t)(p3 & 1023) * HD + cl);
            ACC1(h0, g0, p0 >> 10);
            ACC1(h1, g1, p1 >> 10);
            ACC1(h2, g2, p2 >> 10);
            ACC1(h3, g3, p3 >> 10);
        }
        for (; e < e1; ++e) {
            int s0 = esrc[e];
            int p0 = epack[e];
            uint32_t h0 = *(const uint32_t*)(h_bf + (size_t)s0 * HD + cl);
            uint32_t g0 = *(const uint32_t*)(gb + (size_t)(p0 & 1023) * HD + cl);
            ACC1(h0, g0, p0 >> 10);
        }
        #undef ACC1
    }
    // packed bf16 write: one dword per lane per type
    {
        uint32_t w0 = (uint32_t)(uint16_t)f2bf(a0x) | ((uint32_t)(uint16_t)f2bf(a0y) << 16);
        uint32_t w1 = (uint32_t)(uint16_t)f2bf(a1x) | ((uint32_t)(uint16_t)f2bf(a1y) << 16);
        uint32_t w2 = (uint32_t)(uint16_t)f2bf(a2x) | ((uint32_t)(uint16_t)f2bf(a2y) << 16);
        *(uint32_t*)(S + (0 * 16 + wave) * 136 + cl) = w0;
        *(uint32_t*)(S + (1 * 16 + wave) * 136 + cl) = w1;
        *(uint32_t*)(S + (2 * 16 + wave) * 136 + cl) = w2;
    }
    __syncthreads();

    // ---- MFMA phase: waves 0-7, wave w -> cols w*16 .. w*16+15 ----
    if (wave >= 8) return;
    int quad = lane >> 4, m = lane & 15;
    int c0 = wave * 16;

    f32x4 acc = {0.f, 0.f, 0.f, 0.f};
    #pragma unroll
    for (int t = 0; t < 3; ++t)
        #pragma unroll
        for (int c = 0; c < 4; ++c) {
            bf16x8 a = *(const bf16x8*)(S + (t * 16 + m) * 136 + c * 32 + quad * 8);
            bf16x8 b = *(const bf16x8*)(WtT + ((size_t)t * HD + c0 + m) * HD + c * 32 + quad * 8);
            acc = __builtin_amdgcn_mfma_f32_16x16x32_bf16(a, b, acc, 0, 0, 0);
        }

    int col = c0 + m;
    float bt0 = bt[col], bt1 = bt[HD + col], bt2 = bt[2 * HD + col];
    #pragma unroll
    for (int r = 0; r < 4; ++r) {
        int dd = d0 + quad * 4 + r;
        if (dd < N) {
            float4 cp = cntp[dd];
            float v = (acc[r] + cp.x * bt0 + cp.y * bt1 + cp.z * bt2) * cp.w;
            agg_bf[(size_t)dd * HD + col] = f2bf(v);
        }
    }
}

// fully fused GRU via MFMA; in-place update of h (fp32) and h_bf (bf16)
__launch_bounds__(256)
__global__ void k_gru(const short* __restrict__ agg_bf, short* __restrict__ h_bf,
                      const short* __restrict__ Wihb, const short* __restrict__ Whhb,
                      const float* __restrict__ bih, const float* __restrict__ bhh,
                      float* __restrict__ h, int N) {
    int tid = threadIdx.x;
    int wave = tid >> 6, lane = tid & 63;
    int quad = lane >> 4, m = lane & 15;
    int row0 = blockIdx.x * 16;
    int arow = min(row0 + m, N - 1);

    bf16x8 fa[4], fh[4];
    #pragma unroll
    for (int c = 0; c < 4; ++c) {
        fa[c] = *(const bf16x8*)(agg_bf + (size_t)arow * HD + c * 32 + quad * 8);
        fh[c] = *(const bf16x8*)(h_bf + (size_t)arow * HD + c * 32 + quad * 8);
    }

    f32x4 acc[2][6];
    const f32x4 z4 = {0.f, 0.f, 0.f, 0.f};
    #pragma unroll
    for (int s = 0; s < 2; ++s)
        #pragma unroll
        for (int g = 0; g < 6; ++g) acc[s][g] = z4;

    #pragma unroll
    for (int s = 0; s < 2; ++s) {
        int c0 = (wave * 2 + s) * 16;
        #pragma unroll
        for (int g = 0; g < 3; ++g)
            #pragma unroll
            for (int c = 0; c < 4; ++c) {
                bf16x8 bi = *(const bf16x8*)(Wihb + ((size_t)g * HD + c0 + m) * HD + c * 32 + quad * 8);
                acc[s][g] = __builtin_amdgcn_mfma_f32_16x16x32_bf16(fa[c], bi, acc[s][g], 0, 0, 0);
                bf16x8 bh = *(const bf16x8*)(Whhb + ((size_t)g * HD + c0 + m) * HD + c * 32 + quad * 8);
                acc[s][3 + g] = __builtin_amdgcn_mfma_f32_16x16x32_bf16(fh[c], bh, acc[s][3 + g], 0, 0, 0);
            }
    }

    __syncthreads(); // all h_bf A-frag reads complete before in-place stores

    #pragma unroll
    for (int s = 0; s < 2; ++s) {
        int col = (wave * 2 + s) * 16 + m;
        float bir = bih[col],          bhr = bhh[col];
        float biz = bih[HD + col],     bhz = bhh[HD + col];
        float bin = bih[2 * HD + col], bhn = bhh[2 * HD + col];
        #pragma unroll
        for (int r = 0; r < 4; ++r) {
            int row = row0 + quad * 4 + r;
            if (row < N) {
                float rr = sigm(acc[s][0][r] + bir + acc[s][3][r] + bhr);
                float zz = sigm(acc[s][1][r] + biz + acc[s][4][r] + bhz);
                float nn = tanhf(acc[s][2][r] + bin + rr * (acc[s][5][r] + bhn));
                size_t idx = (size_t)row * HD + col;
                float hv = h[idx];
                float hp = (1.0f - zz) * nn + zz * hv;
                h[idx] = hp;
                h_bf[idx] = f2bf(hp);
            }
        }
    }
}

// feats=[h|emb[x]|sel] (bf16 frags) @ W1T (MFMA) -> relu -> @W2 + b2
__launch_bounds__(256)
__global__ void k_final(const short* __restrict__ h_bf, const int* __restrict__ xidx,
                        const float* __restrict__ sel, const float* __restrict__ emb,
                        const short* __restrict__ W1T, const float* __restrict__ b1,
                        const float* __restrict__ W2, const float* __restrict__ b2,
                        float* __restrict__ out, int N) {
    __shared__ float red[4][16];
    int tid = threadIdx.x;
    int wave = tid >> 6, lane = tid & 63;
    int quad = lane >> 4, m = lane & 15;
    int row0 = blockIdx.x * 16;
    int arow = min(row0 + m, N - 1);
    int xi = xidx[arow];

    bf16x8 fa[8];
    #pragma unroll
    for (int c = 0; c < 4; ++c)
        fa[c] = *(const bf16x8*)(h_bf + (size_t)arow * HD + c * 32 + quad * 8);
    #pragma unroll
    for (int c = 4; c < 7; ++c) {
        const float* ep = emb + (size_t)xi * EMBD + (c - 4) * 32 + quad * 8;
        #pragma unroll
        for (int j = 0; j < 8; ++j) fa[c][j] = f2bf(ep[j]);
    }
    {
        const float* sp = sel + (size_t)arow * SELD + quad * 8;
        #pragma unroll
        for (int j = 0; j < 8; ++j) fa[7][j] = f2bf(sp[j]);
    }

    f32x4 acc[2];
    const f32x4 z4 = {0.f, 0.f, 0.f, 0.f};
    acc[0] = z4; acc[1] = z4;
    #pragma unroll
    for (int s = 0; s < 2; ++s) {
        int c0 = (wave * 2 + s) * 16;
        #pragma unroll
        for (int c = 0; c < 8; ++c) {
            bf16x8 b = *(const bf16x8*)(W1T + (size_t)(c0 + m) * (2 * HD) + c * 32 + quad * 8);
            acc[s] = __builtin_amdgcn_mfma_f32_16x16x32_bf16(fa[c], b, acc[s], 0, 0, 0);
        }
    }

    float psum[4] = {0.f, 0.f, 0.f, 0.f};
    #pragma unroll
    for (int s = 0; s < 2; ++s) {
        int col = (wave * 2 + s) * 16 + m;
        float b1v = b1[col], w2v = W2[col];
        #pragma unroll
        for (int r = 0; r < 4; ++r)
            psum[r] += fmaxf(acc[s][r] + b1v, 0.0f) * w2v;
    }
    #pragma unroll
    for (int off = 1; off < 16; off <<= 1)
        #pragma unroll
        for (int r = 0; r < 4; ++r) psum[r] += __shfl_xor(psum[r], off);

    if (m == 0) {
        #pragma unroll
        for (int r = 0; r < 4; ++r) red[wave][quad * 4 + r] = psum[r];
    }
    __syncthreads();
    if (tid < 16) {
        int row = row0 + tid;
        if (row < N) out[row] = red[0][tid] + red[1][tid] + red[2][tid] + red[3][tid] + b2[0];
    }
}

// ---------------- launcher ----------------

extern "C" void kernel_launch(void* const* d_in, const int* in_sizes, int n_in,
                              void* d_out, int out_size, void* d_ws, size_t ws_size,
                              hipStream_t stream) {
    const int*   xidx = (const int*)d_in[0];
    const float* sel  = (const float*)d_in[1];
    const int*   ei   = (const int*)d_in[2];
    const int*   et   = (const int*)d_in[3];
    const int*   ep   = (const int*)d_in[4];
    const float* emb  = (const float*)d_in[5];
    const float* pe   = (const float*)d_in[6];
    const float* Wg   = (const float*)d_in[7];
    const float* bg   = (const float*)d_in[8];
    const float* Wt   = (const float*)d_in[9];
    const float* bt   = (const float*)d_in[10];
    const float* Wih  = (const float*)d_in[11];
    const float* Whh  = (const float*)d_in[12];
    const float* bih  = (const float*)d_in[13];
    const float* bhh  = (const float*)d_in[14];
    const float* W1   = (const float*)d_in[15];
    const float* b1   = (const float*)d_in[16];
    const float* W2   = (const float*)d_in[17];
    const float* b2   = (const float*)d_in[18];

    const int N = in_sizes[0];
    const int E = in_sizes[3];
    const size_t NH = (size_t)N * HD;

    char* p = (char*)d_ws;
    float*  h      = (float*)p;  p += NH * 4;
    short*  agg_bf = (short*)p;  p += NH * 2;
    short*  h_bf   = (short*)p;  p += NH * 2;
    short*  gb     = (short*)p;  p += (size_t)NPOS * HD * 2;
    short*  WtT    = (short*)p;  p += 3 * HD * HD * 2;
    short*  Wihb   = (short*)p;  p += 3 * HD * HD * 2;
    short*  Whhb   = (short*)p;  p += 3 * HD * HD * 2;
    short*  W1T    = (short*)p;  p += 2 * HD * HD * 2;
    float4* cntp   = (float4*)p; p += (size_t)N * 16;
    int* deg    = (int*)p; p += (size_t)N * 4;
    int* cnt_t  = (int*)p; p += 3 * (size_t)N * 4;
    int* rp     = (int*)p; p += (size_t)(N + 1) * 4;
    int* cursor = (int*)p; p += (size_t)N * 4;
    int* esrc   = (int*)p; p += (size_t)E * 4;
    int* epack  = (int*)p;

    // ---- setup ----
    hipMemsetAsync(deg, 0, (size_t)N * sizeof(int), stream);
    hipMemsetAsync(cnt_t, 0, 3 * (size_t)N * sizeof(int), stream);
    hipMemsetAsync(cursor, 0, (size_t)N * sizeof(int), stream);
    k_deg<<<(E + 255) / 256, 256, 0, stream>>>(ei, et, deg, cnt_t, E, N);
    k_cntp<<<(N + 255) / 256, 256, 0, stream>>>(deg, cnt_t, cntp, N);
    k_scan<<<1, 1024, 0, stream>>>(deg, rp, N, E);
    k_fill<<<(E + 255) / 256, 256, 0, stream>>>(ei, et, ep, rp, cursor, esrc, epack, E);
    k_gate<<<NPOS, HD, 0, stream>>>(pe, Wg, bg, gb);
    k_prep<<<(3 * 3 * HD * HD + 2 * HD * HD + 255) / 256, 256, 0, stream>>>(
        Wt, Wih, Whh, W1, WtT, Wihb, Whhb, W1T);
    k_init<<<(N * HD + 255) / 256, 256, 0, stream>>>(xidx, sel, emb, h, h_bf, N);

    const int gB = (N + 15) / 16;
    for (int it = 0; it < GITERS; ++it) {
        k_agg<<<gB, 1024, 0, stream>>>(rp, esrc, epack, h_bf, gb, WtT, bt, cntp, agg_bf, N);
        k_gru<<<gB, 256, 0, stream>>>(agg_bf, h_bf, Wihb, Whhb, bih, bhh, h, N);
    }

    k_final<<<gB, 256, 0, stream>>>(h_bf, xidx, sel, emb, W1T, b1, W2, b2, (float*)d_out, N);
}

// Round 5
// 2050.455 us; speedup vs baseline: 3.8553x; 1.1250x over previous
//
#include <hip/hip_runtime.h>
#include <cstdint>
#include <cstddef>

#define HD 128
#define EMBD 96
#define SELD 32
#define PD 64
#define NPOS 513
#define GITERS 6

typedef __attribute__((ext_vector_type(8))) short bf16x8;
typedef __attribute__((ext_vector_type(4))) float f32x4;

__device__ __forceinline__ float sigm(float x) { return 1.0f / (1.0f + __expf(-x)); }

__device__ __forceinline__ short f2bf(float x) {
    uint32_t u = __float_as_uint(x);
    uint32_t r = (u + 0x7fffu + ((u >> 16) & 1u)) >> 16;
    return (short)r;
}
__device__ __forceinline__ float bf2f(uint32_t s) {
    return __uint_as_float(s << 16);
}

// ---------------- setup kernels ----------------

__global__ void k_deg(const int* __restrict__ ei, const int* __restrict__ et,
                      int* __restrict__ deg, int* __restrict__ cnt_t, int E, int N) {
    int e = blockIdx.x * 256 + threadIdx.x;
    if (e < E) {
        int d = ei[E + e];
        atomicAdd(&deg[d], 1);
        atomicAdd(&cnt_t[(size_t)et[e] * N + d], 1);
    }
}

__global__ void k_cntp(const int* __restrict__ deg, const int* __restrict__ cnt_t,
                       float4* __restrict__ cntp, int N) {
    int n = blockIdx.x * 256 + threadIdx.x;
    if (n < N) {
        float4 v;
        v.x = (float)cnt_t[n];
        v.y = (float)cnt_t[(size_t)N + n];
        v.z = (float)cnt_t[2 * (size_t)N + n];
        v.w = 1.0f / fmaxf((float)deg[n], 1.0f);
        cntp[n] = v;
    }
}

__launch_bounds__(1024)
__global__ void k_scan(const int* __restrict__ deg, int* __restrict__ rp, int N, int E) {
    __shared__ int sc[1024];
    int t = threadIdx.x;
    int chunk = (N + 1023) / 1024;
    int lo = t * chunk, hi = min(N, lo + chunk);
    int sum = 0;
    for (int i = lo; i < hi; ++i) sum += deg[i];
    sc[t] = sum;
    __syncthreads();
    for (int off = 1; off < 1024; off <<= 1) {
        int v = (t >= off) ? sc[t - off] : 0;
        __syncthreads();
        sc[t] += v;
        __syncthreads();
    }
    int base = sc[t] - sum;
    int run = base;
    for (int i = lo; i < hi; ++i) { rp[i] = run; run += deg[i]; }
    if (t == 1023) rp[N] = base + sum;
}

__global__ void k_fill(const int* __restrict__ ei, const int* __restrict__ et,
                       const int* __restrict__ ep, const int* __restrict__ rp,
                       int* __restrict__ cursor, int* __restrict__ esrc,
                       int* __restrict__ epack, int E) {
    int e = blockIdx.x * 256 + threadIdx.x;
    if (e < E) {
        int d = ei[E + e];
        int pos = atomicAdd(&cursor[d], 1);
        int idx = rp[d] + pos;
        esrc[idx] = ei[e];
        epack[idx] = (et[e] << 10) | ep[e];
    }
}

__global__ void k_gate(const float* __restrict__ pe, const float* __restrict__ Wg,
                       const float* __restrict__ bg, short* __restrict__ gb) {
    int p = blockIdx.x;
    int j = threadIdx.x;
    float acc = bg[j];
    #pragma unroll 8
    for (int k = 0; k < PD; ++k) acc += pe[p * PD + k] * Wg[k * HD + j];
    gb[p * HD + j] = f2bf(2.0f * sigm(acc));
}

__global__ void k_prep(const float* __restrict__ Wt, const float* __restrict__ Wih,
                       const float* __restrict__ Whh, const float* __restrict__ W1,
                       short* __restrict__ WtT, short* __restrict__ Wihb,
                       short* __restrict__ Whhb, short* __restrict__ W1T) {
    const int SZ = 3 * HD * HD;
    int id = blockIdx.x * 256 + threadIdx.x;
    if (id < SZ) {
        int t = id / (HD * HD), rem = id % (HD * HD);
        int n = rem / HD, k = rem % HD;
        WtT[id] = f2bf(Wt[t * HD * HD + k * HD + n]);
    } else if (id < 2 * SZ) {
        int i2 = id - SZ;
        Wihb[i2] = f2bf(Wih[i2]);
    } else if (id < 3 * SZ) {
        int i2 = id - 2 * SZ;
        Whhb[i2] = f2bf(Whh[i2]);
    } else if (id < 3 * SZ + 2 * HD * HD) {
        int rem = id - 3 * SZ;
        int n = rem / (2 * HD), k = rem % (2 * HD);
        W1T[rem] = f2bf(W1[k * HD + n]);
    }
}

__global__ void k_init(const int* __restrict__ xidx, const float* __restrict__ sel,
                       const float* __restrict__ emb, float* __restrict__ h,
                       short* __restrict__ h_bf, int N) {
    int id = blockIdx.x * 256 + threadIdx.x;
    if (id < N * HD) {
        int n = id >> 7, j = id & 127;
        float v = (j < EMBD) ? emb[(size_t)xidx[n] * EMBD + j]
                             : sel[(size_t)n * SELD + (j - EMBD)];
        h[id] = v;
        h_bf[id] = f2bf(v);
    }
}

// ---------------- fused per-iteration kernel ----------------
// 1024 threads = 16 waves, 16 dst rows per block.
// P1: wave w gathers row w's edges -> per-type bf16 sums S; own h rows -> hL.
// P2: waves 0-7: agg MFMA + epilogue -> aggL.  waves 8-15: h@Whh -> ahL.
// P3: waves 0-7: agg@Wih + combine + GRU epilogue -> h fp32 + hOut.
// P4: all: coalesced copy hOut -> h_bf_out.
__launch_bounds__(1024, 8)
__global__ void k_iter(const int* __restrict__ rp, const int* __restrict__ esrc,
                       const int* __restrict__ epack, const short* __restrict__ h_in,
                       const short* __restrict__ gb, const short* __restrict__ WtT,
                       const float* __restrict__ bt, const float4* __restrict__ cntp,
                       const short* __restrict__ Wihb, const short* __restrict__ Whhb,
                       const float* __restrict__ bih, const float* __restrict__ bhh,
                       float* __restrict__ h, short* __restrict__ h_out, int N) {
    __shared__ short S[3 * 16 * 136];
    __shared__ short hL[16 * 136];
    __shared__ short aggL[16 * 136];
    __shared__ short hOut[16 * 136];
    __shared__ float ahL[8][3][64][4];

    int tid = threadIdx.x;
    int wave = tid >> 6, lane = tid & 63;
    int quad = lane >> 4, m = lane & 15;
    int d0 = blockIdx.x * 16;

    // ---- P1: stage own h rows (wave w copies row w, lane l copies dword l)
    {
        int srow = min(d0 + wave, N - 1);
        uint32_t v = *(const uint32_t*)(h_in + (size_t)srow * HD + 2 * lane);
        *(uint32_t*)(hL + wave * 136 + 2 * lane) = v;
    }

    // ---- P1: gather (one dst row per wave)
    {
        int d = __builtin_amdgcn_readfirstlane(min(d0 + wave, N - 1));
        bool valid = (d0 + wave) < N;
        float a0x = 0.f, a0y = 0.f, a1x = 0.f, a1y = 0.f, a2x = 0.f, a2y = 0.f;
        int cl = 2 * lane;
        if (valid) {
            int e = rp[d], e1 = rp[d + 1];
            #define ACC1(hv, gv, t)                                              \
                {                                                                \
                    float mx = bf2f((hv) & 0xffffu) * bf2f((gv) & 0xffffu);      \
                    float my = bf2f((hv) >> 16) * bf2f((gv) >> 16);              \
                    if ((t) == 0)      { a0x += mx; a0y += my; }                 \
                    else if ((t) == 1) { a1x += mx; a1y += my; }                 \
                    else               { a2x += mx; a2y += my; }                 \
                }
            for (; e + 4 <= e1; e += 4) {
                int s0 = esrc[e],  s1 = esrc[e + 1], s2 = esrc[e + 2], s3 = esrc[e + 3];
                int p0 = epack[e], p1 = epack[e + 1], p2 = epack[e + 2], p3 = epack[e + 3];
                uint32_t h0 = *(const uint32_t*)(h_in + (size_t)s0 * HD + cl);
                uint32_t h1 = *(const uint32_t*)(h_in + (size_t)s1 * HD + cl);
                uint32_t h2 = *(const uint32_t*)(h_in + (size_t)s2 * HD + cl);
                uint32_t h3 = *(const uint32_t*)(h_in + (size_t)s3 * HD + cl);
                uint32_t g0 = *(const uint32_t*)(gb + (size_t)(p0 & 1023) * HD + cl);
                uint32_t g1 = *(const uint32_t*)(gb + (size_t)(p1 & 1023) * HD + cl);
                uint32_t g2 = *(const uint32_t*)(gb + (size_t)(p2 & 1023) * HD + cl);
                uint32_t g3 = *(const uint32_t*)(gb + (size_t)(p3 & 1023) * HD + cl);
                ACC1(h0, g0, p0 >> 10);
                ACC1(h1, g1, p1 >> 10);
                ACC1(h2, g2, p2 >> 10);
                ACC1(h3, g3, p3 >> 10);
            }
            for (; e < e1; ++e) {
                int s0 = esrc[e];
                int p0 = epack[e];
                uint32_t h0 = *(const uint32_t*)(h_in + (size_t)s0 * HD + cl);
                uint32_t g0 = *(const uint32_t*)(gb + (size_t)(p0 & 1023) * HD + cl);
                ACC1(h0, g0, p0 >> 10);
            }
            #undef ACC1
        }
        uint32_t w0 = (uint32_t)(uint16_t)f2bf(a0x) | ((uint32_t)(uint16_t)f2bf(a0y) << 16);
        uint32_t w1 = (uint32_t)(uint16_t)f2bf(a1x) | ((uint32_t)(uint16_t)f2bf(a1y) << 16);
        uint32_t w2 = (uint32_t)(uint16_t)f2bf(a2x) | ((uint32_t)(uint16_t)f2bf(a2y) << 16);
        *(uint32_t*)(S + (0 * 16 + wave) * 136 + cl) = w0;
        *(uint32_t*)(S + (1 * 16 + wave) * 136 + cl) = w1;
        *(uint32_t*)(S + (2 * 16 + wave) * 136 + cl) = w2;
    }
    __syncthreads();

    // ---- P2
    if (wave < 8) {
        // agg MFMA: cols wave*16..+15
        int c0 = wave * 16;
        f32x4 acc = {0.f, 0.f, 0.f, 0.f};
        #pragma unroll
        for (int t = 0; t < 3; ++t)
            #pragma unroll
            for (int c = 0; c < 4; ++c) {
                bf16x8 a = *(const bf16x8*)(S + (t * 16 + m) * 136 + c * 32 + quad * 8);
                bf16x8 b = *(const bf16x8*)(WtT + ((size_t)t * HD + c0 + m) * HD + c * 32 + quad * 8);
                acc = __builtin_amdgcn_mfma_f32_16x16x32_bf16(a, b, acc, 0, 0, 0);
            }
        int col = c0 + m;
        float bt0 = bt[col], bt1 = bt[HD + col], bt2 = bt[2 * HD + col];
        #pragma unroll
        for (int r = 0; r < 4; ++r) {
            int mm = quad * 4 + r;
            int dd = min(d0 + mm, N - 1);
            float4 cp = cntp[dd];
            float v = (acc[r] + cp.x * bt0 + cp.y * bt1 + cp.z * bt2) * cp.w;
            aggL[mm * 136 + col] = f2bf(v);
        }
    } else {
        // h @ Whh for cols (wave-8)*16..+15
        int sw = wave - 8;
        int c0 = sw * 16;
        bf16x8 fh[4];
        #pragma unroll
        for (int c = 0; c < 4; ++c)
            fh[c] = *(const bf16x8*)(hL + m * 136 + c * 32 + quad * 8);
        f32x4 ah[3];
        const f32x4 z4 = {0.f, 0.f, 0.f, 0.f};
        ah[0] = z4; ah[1] = z4; ah[2] = z4;
        #pragma unroll
        for (int g = 0; g < 3; ++g)
            #pragma unroll
            for (int c = 0; c < 4; ++c) {
                bf16x8 b = *(const bf16x8*)(Whhb + ((size_t)g * HD + c0 + m) * HD + c * 32 + quad * 8);
                ah[g] = __builtin_amdgcn_mfma_f32_16x16x32_bf16(fh[c], b, ah[g], 0, 0, 0);
            }
        #pragma unroll
        for (int g = 0; g < 3; ++g)
            *(f32x4*)&ahL[sw][g][lane][0] = ah[g];
    }
    __syncthreads();

    // ---- P3: waves 0-7: agg @ Wih + combine + GRU epilogue
    if (wave < 8) {
        int c0 = wave * 16;
        bf16x8 fa[4];
        #pragma unroll
        for (int c = 0; c < 4; ++c)
            fa[c] = *(const bf16x8*)(aggL + m * 136 + c * 32 + quad * 8);
        f32x4 ai[3];
        const f32x4 z4 = {0.f, 0.f, 0.f, 0.f};
        ai[0] = z4; ai[1] = z4; ai[2] = z4;
        #pragma unroll
        for (int g = 0; g < 3; ++g)
            #pragma unroll
            for (int c = 0; c < 4; ++c) {
                bf16x8 b = *(const bf16x8*)(Wihb + ((size_t)g * HD + c0 + m) * HD + c * 32 + quad * 8);
                ai[g] = __builtin_amdgcn_mfma_f32_16x16x32_bf16(fa[c], b, ai[g], 0, 0, 0);
            }
        f32x4 ah[3];
        #pragma unroll
        for (int g = 0; g < 3; ++g)
            ah[g] = *(const f32x4*)&ahL[wave][g][lane][0];

        int col = c0 + m;
        float bir = bih[col],          bhr = bhh[col];
        float biz = bih[HD + col],     bhz = bhh[HD + col];
        float bin = bih[2 * HD + col], bhn = bhh[2 * HD + col];
        #pragma unroll
        for (int r = 0; r < 4; ++r) {
            int row = quad * 4 + r;
            int grow = d0 + row;
            if (grow < N) {
                float rr = sigm(ai[0][r] + bir + ah[0][r] + bhr);
                float zz = sigm(ai[1][r] + biz + ah[1][r] + bhz);
                float nn = tanhf(ai[2][r] + bin + rr * (ah[2][r] + bhn));
                size_t idx = (size_t)grow * HD + col;
                float hv = h[idx];
                float hp = (1.0f - zz) * nn + zz * hv;
                h[idx] = hp;
                hOut[row * 136 + col] = f2bf(hp);
            }
        }
    }
    __syncthreads();

    // ---- P4: coalesced copy hOut -> h_out (wave w copies row w)
    if (d0 + wave < N) {
        uint32_t v = *(const uint32_t*)(hOut + wave * 136 + 2 * lane);
        *(uint32_t*)(h_out + (size_t)(d0 + wave) * HD + 2 * lane) = v;
    }
}

// feats=[h|emb[x]|sel] (bf16 frags) @ W1T (MFMA) -> relu -> @W2 + b2
__launch_bounds__(256)
__global__ void k_final(const short* __restrict__ h_bf, const int* __restrict__ xidx,
                        const float* __restrict__ sel, const float* __restrict__ emb,
                        const short* __restrict__ W1T, const float* __restrict__ b1,
                        const float* __restrict__ W2, const float* __restrict__ b2,
                        float* __restrict__ out, int N) {
    __shared__ float red[4][16];
    int tid = threadIdx.x;
    int wave = tid >> 6, lane = tid & 63;
    int quad = lane >> 4, m = lane & 15;
    int row0 = blockIdx.x * 16;
    int arow = min(row0 + m, N - 1);
    int xi = xidx[arow];

    bf16x8 fa[8];
    #pragma unroll
    for (int c = 0; c < 4; ++c)
        fa[c] = *(const bf16x8*)(h_bf + (size_t)arow * HD + c * 32 + quad * 8);
    #pragma unroll
    for (int c = 4; c < 7; ++c) {
        const float* ep = emb + (size_t)xi * EMBD + (c - 4) * 32 + quad * 8;
        #pragma unroll
        for (int j = 0; j < 8; ++j) fa[c][j] = f2bf(ep[j]);
    }
    {
        const float* sp = sel + (size_t)arow * SELD + quad * 8;
        #pragma unroll
        for (int j = 0; j < 8; ++j) fa[7][j] = f2bf(sp[j]);
    }

    f32x4 acc[2];
    const f32x4 z4 = {0.f, 0.f, 0.f, 0.f};
    acc[0] = z4; acc[1] = z4;
    #pragma unroll
    for (int s = 0; s < 2; ++s) {
        int c0 = (wave * 2 + s) * 16;
        #pragma unroll
        for (int c = 0; c < 8; ++c) {
            bf16x8 b = *(const bf16x8*)(W1T + (size_t)(c0 + m) * (2 * HD) + c * 32 + quad * 8);
            acc[s] = __builtin_amdgcn_mfma_f32_16x16x32_bf16(fa[c], b, acc[s], 0, 0, 0);
        }
    }

    float psum[4] = {0.f, 0.f, 0.f, 0.f};
    #pragma unroll
    for (int s = 0; s < 2; ++s) {
        int col = (wave * 2 + s) * 16 + m;
        float b1v = b1[col], w2v = W2[col];
        #pragma unroll
        for (int r = 0; r < 4; ++r)
            psum[r] += fmaxf(acc[s][r] + b1v, 0.0f) * w2v;
    }
    #pragma unroll
    for (int off = 1; off < 16; off <<= 1)
        #pragma unroll
        for (int r = 0; r < 4; ++r) psum[r] += __shfl_xor(psum[r], off);

    if (m == 0) {
        #pragma unroll
        for (int r = 0; r < 4; ++r) red[wave][quad * 4 + r] = psum[r];
    }
    __syncthreads();
    if (tid < 16) {
        int row = row0 + tid;
        if (row < N) out[row] = red[0][tid] + red[1][tid] + red[2][tid] + red[3][tid] + b2[0];
    }
}

// ---------------- launcher ----------------

extern "C" void kernel_launch(void* const* d_in, const int* in_sizes, int n_in,
                              void* d_out, int out_size, void* d_ws, size_t ws_size,
                              hipStream_t stream) {
    const int*   xidx = (const int*)d_in[0];
    const float* sel  = (const float*)d_in[1];
    const int*   ei   = (const int*)d_in[2];
    const int*   et   = (const int*)d_in[3];
    const int*   ep   = (const int*)d_in[4];
    const float* emb  = (const float*)d_in[5];
    const float* pe   = (const float*)d_in[6];
    const float* Wg   = (const float*)d_in[7];
    const float* bg   = (const float*)d_in[8];
    const float* Wt   = (const float*)d_in[9];
    const float* bt   = (const float*)d_in[10];
    const float* Wih  = (const float*)d_in[11];
    const float* Whh  = (const float*)d_in[12];
    const float* bih  = (const float*)d_in[13];
    const float* bhh  = (const float*)d_in[14];
    const float* W1   = (const float*)d_in[15];
    const float* b1   = (const float*)d_in[16];
    const float* W2   = (const float*)d_in[17];
    const float* b2   = (const float*)d_in[18];

    const int N = in_sizes[0];
    const int E = in_sizes[3];
    const size_t NH = (size_t)N * HD;

    char* p = (char*)d_ws;
    float*  h     = (float*)p;  p += NH * 4;
    short*  hbf0  = (short*)p;  p += NH * 2;
    short*  hbf1  = (short*)p;  p += NH * 2;
    short*  gb    = (short*)p;  p += (size_t)NPOS * HD * 2;
    short*  WtT   = (short*)p;  p += 3 * HD * HD * 2;
    short*  Wihb  = (short*)p;  p += 3 * HD * HD * 2;
    short*  Whhb  = (short*)p;  p += 3 * HD * HD * 2;
    short*  W1T   = (short*)p;  p += 2 * HD * HD * 2;
    float4* cntp  = (float4*)p; p += (size_t)N * 16;
    int* deg    = (int*)p; p += (size_t)N * 4;
    int* cnt_t  = (int*)p; p += 3 * (size_t)N * 4;
    int* rp     = (int*)p; p += (size_t)(N + 1) * 4;
    int* cursor = (int*)p; p += (size_t)N * 4;
    int* esrc   = (int*)p; p += (size_t)E * 4;
    int* epack  = (int*)p;

    // ---- setup ----
    hipMemsetAsync(deg, 0, (size_t)N * sizeof(int), stream);
    hipMemsetAsync(cnt_t, 0, 3 * (size_t)N * sizeof(int), stream);
    hipMemsetAsync(cursor, 0, (size_t)N * sizeof(int), stream);
    k_deg<<<(E + 255) / 256, 256, 0, stream>>>(ei, et, deg, cnt_t, E, N);
    k_cntp<<<(N + 255) / 256, 256, 0, stream>>>(deg, cnt_t, cntp, N);
    k_scan<<<1, 1024, 0, stream>>>(deg, rp, N, E);
    k_fill<<<(E + 255) / 256, 256, 0, stream>>>(ei, et, ep, rp, cursor, esrc, epack, E);
    k_gate<<<NPOS, HD, 0, stream>>>(pe, Wg, bg, gb);
    k_prep<<<(3 * 3 * HD * HD + 2 * HD * HD + 255) / 256, 256, 0, stream>>>(
        Wt, Wih, Whh, W1, WtT, Wihb, Whhb, W1T);
    k_init<<<(N * HD + 255) / 256, 256, 0, stream>>>(xidx, sel, emb, h, hbf0, N);

    const int gB = (N + 15) / 16;
    const short* hin = hbf0;
    short* hout = hbf1;
    for (int it = 0; it < GITERS; ++it) {
        k_iter<<<gB, 1024, 0, stream>>>(rp, esrc, epack, hin, gb, WtT, bt, cntp,
                                        Wihb, Whhb, bih, bhh, h, hout, N);
        const short* tmp = hout;
        hout = (short*)hin;
        hin = tmp;
    }

    k_final<<<gB, 256, 0, stream>>>(hin, xidx, sel, emb, W1T, b1, W2, b2, (float*)d_out, N);
}